// Round 2
// baseline (428.389 us; speedup 1.0000x reference)
//
#include <hip/hip_runtime.h>
#include <hip/hip_bf16.h>
#include <hip/hip_fp16.h>

#define B_ 512
#define L_ 20
#define NS_ 16
#define EPS_ 32
#define H_ 128
#define V_ 100000
#define N_NODES (B_*NS_)   // 8192
#define N_EDGES (B_*EPS_)  // 16384
#define NV (V_-1)          // 99999

typedef _Float16 half8 __attribute__((ext_vector_type(8)));
typedef float floatx4 __attribute__((ext_vector_type(4)));

#define PITCH 136  // 128 f16 + 8 pad -> 272B row, 4-bank rotation, 2-way max (free)

// ---------------- K1: weight conversions + node feature gather ----------------
__global__ void k_prep(const int* __restrict__ items, const float* __restrict__ emb,
                       const float* __restrict__ Wg, const float* __restrict__ Whh,
                       const float* __restrict__ Wih, const float* __restrict__ W2,
                       const float* __restrict__ W1,
                       float* __restrict__ x, _Float16* __restrict__ WgT_h,
                       _Float16* __restrict__ Whh_h, _Float16* __restrict__ Wih_h,
                       _Float16* __restrict__ W2_h, _Float16* __restrict__ W1_h) {
  int i = blockIdx.x*256 + threadIdx.x;
  if (i < N_NODES*H_) {          // x = embedding[items]
    int n = i >> 7, h = i & 127;
    x[i] = emb[(size_t)items[n]*H_ + h];
    return;
  }
  i -= N_NODES*H_;
  if (i < H_*H_) { int j = i>>7, k = i&127; WgT_h[i] = (_Float16)Wg[k*H_ + j]; return; }
  i -= H_*H_;
  if (i < 3*H_*H_) { Whh_h[i] = (_Float16)Whh[i]; return; }
  i -= 3*H_*H_;
  if (i < 3*H_*H_) { Wih_h[i] = (_Float16)Wih[i]; return; }
  i -= 3*H_*H_;
  if (i < H_*H_) { W2_h[i] = (_Float16)W2[i]; return; }
  i -= H_*H_;
  if (i < H_*H_) { W1_h[i] = (_Float16)W1[i]; return; }
}

// ---------------- generic K=128 f16-MFMA GEMM: C[M,N] = A[M,128] * B[N,128]^T ----
// A fp32 (converted on load), B f16 row-major [N][128]. 64x64 block tile, 4 waves.
// B pointer switches to B1 for m-tiles >= switch_mt (used for the q1/q2 fused GEMM).
__global__ __launch_bounds__(256) void k_gemm128(
    const float* __restrict__ A, const _Float16* __restrict__ B0,
    const _Float16* __restrict__ B1, int switch_mt,
    float* __restrict__ C, int N) {
  __shared__ _Float16 lds_a[64*PITCH];
  __shared__ _Float16 lds_b[64*PITCH];
  const int tid = threadIdx.x;
  const int mt = blockIdx.y, nt = blockIdx.x;
  const _Float16* __restrict__ Bp = (mt < switch_mt) ? B0 : B1;
  // stage A (64x128 fp32 -> f16): 64 rows x 32 float4-chunks = 2048 = 8*256
  #pragma unroll
  for (int i = 0; i < 8; i++) {
    int lin = i*256 + tid;
    int row = lin >> 5, c4 = lin & 31;
    const float4 v = *reinterpret_cast<const float4*>(&A[(size_t)(mt*64+row)*H_ + c4*4]);
    union { _Float16 h[4]; uint2 u; } p;
    p.h[0]=(_Float16)v.x; p.h[1]=(_Float16)v.y; p.h[2]=(_Float16)v.z; p.h[3]=(_Float16)v.w;
    *reinterpret_cast<uint2*>(&lds_a[row*PITCH + c4*4]) = p.u;
  }
  // stage B (64x128 f16): 64 rows x 16 uint4-chunks = 1024 = 4*256  [R1 fix]
  #pragma unroll
  for (int i = 0; i < 4; i++) {
    int lin = i*256 + tid;
    int row = lin >> 4, ch = lin & 15;
    uint4 v = *reinterpret_cast<const uint4*>(&Bp[(size_t)(nt*64+row)*H_ + ch*8]);
    *reinterpret_cast<uint4*>(&lds_b[row*PITCH + ch*8]) = v;
  }
  __syncthreads();
  const int w = tid >> 6, lane = tid & 63, quad = lane >> 4, r16 = lane & 15;
  half8 afr[4];
  #pragma unroll
  for (int kk = 0; kk < 4; kk++)
    afr[kk] = *reinterpret_cast<const half8*>(&lds_a[(w*16 + r16)*PITCH + kk*32 + quad*8]);
  floatx4 acc[4];
  #pragma unroll
  for (int n4 = 0; n4 < 4; n4++) acc[n4] = (floatx4){0.f,0.f,0.f,0.f};
  #pragma unroll
  for (int n4 = 0; n4 < 4; n4++) {
    #pragma unroll
    for (int kk = 0; kk < 4; kk++) {
      half8 bfr = *reinterpret_cast<const half8*>(&lds_b[(n4*16 + r16)*PITCH + kk*32 + quad*8]);
      acc[n4] = __builtin_amdgcn_mfma_f32_16x16x32_f16(afr[kk], bfr, acc[n4], 0, 0, 0);
    }
  }
  #pragma unroll
  for (int n4 = 0; n4 < 4; n4++)
    #pragma unroll
    for (int r = 0; r < 4; r++) {
      int row = mt*64 + w*16 + quad*4 + r;
      int col = nt*64 + n4*16 + r16;
      C[(size_t)row*N + col] = acc[n4][r];
    }
}

// ---------------- K3: per-session edge scatter-add (no atomics) ----------------
// agg[dst] += m[src]; m is cols [0,128) of mgh (row stride 512).
__global__ __launch_bounds__(128) void k_scatter(const int* __restrict__ edge_index,
                                                 const float* __restrict__ mgh,
                                                 float* __restrict__ agg) {
  __shared__ float acc[NS_*H_];
  const int b = blockIdx.x, h = threadIdx.x;
  #pragma unroll
  for (int j = 0; j < NS_; j++) acc[j*H_ + h] = 0.f;
  // each thread owns column h of all 16 rows -> no races, no syncs needed
  for (int e = 0; e < EPS_; e++) {
    int se = edge_index[b*EPS_ + e];
    int de = edge_index[N_EDGES + b*EPS_ + e];
    acc[(de - b*NS_)*H_ + h] += mgh[(size_t)se*512 + h];
  }
  #pragma unroll
  for (int j = 0; j < NS_; j++) agg[(size_t)(b*NS_ + j)*H_ + h] = acc[j*H_ + h];
}

// ---------------- K5: GRU cell elementwise (x updated in place -> xg) ----------
__global__ void k_gru(const float* __restrict__ gi, const float* __restrict__ mgh,
                      const float* __restrict__ b_ih, const float* __restrict__ b_hh,
                      float* __restrict__ x) {
  int i = blockIdx.x*256 + threadIdx.x;  // < 8192*128
  int n = i >> 7, h = i & 127;
  float ir  = gi[(size_t)n*384 + h]        + b_ih[h];
  float iz  = gi[(size_t)n*384 + 128 + h]  + b_ih[128 + h];
  float in_ = gi[(size_t)n*384 + 256 + h]  + b_ih[256 + h];
  float hr  = mgh[(size_t)n*512 + 128 + h] + b_hh[h];
  float hz  = mgh[(size_t)n*512 + 256 + h] + b_hh[128 + h];
  float hn  = mgh[(size_t)n*512 + 384 + h] + b_hh[256 + h];
  float r = 1.f/(1.f + __expf(-(ir + hr)));
  float z = 1.f/(1.f + __expf(-(iz + hz)));
  float nn = tanhf(in_ + r*hn);
  x[i] = (1.f - z)*nn + z*x[i];
}

// ---------------- K6: ragged gather -> Hbuf rows [0,10240)=hidden, [10240,10752)=ht
__global__ void k_hidden(const int* __restrict__ items, const int* __restrict__ sequence,
                         const int* __restrict__ mask, const float* __restrict__ xg,
                         const float* __restrict__ emb, float* __restrict__ Hbuf) {
  int tid = threadIdx.x;
  int r = blockIdx.x*2 + (tid >> 7);
  int h = tid & 127;
  int b, l;
  if (r < B_*L_) { b = r / L_; l = r - b*L_; }
  else {
    b = r - B_*L_;
    int len = 0;
    for (int i = 0; i < L_; i++) len += mask[b*L_ + i];
    l = len - 1;
  }
  int seqv = sequence[b*L_ + l];
  float val = 0.f;
  if (seqv != 0) {
    int idx = -1;
    #pragma unroll
    for (int j = 0; j < NS_; j++) { if (idx < 0 && items[b*NS_ + j] == seqv) idx = j; }
    val = (idx >= 0) ? xg[(size_t)(b*NS_ + idx)*H_ + h] : emb[(size_t)seqv*H_ + h];
  }
  Hbuf[(size_t)r*H_ + h] = val;
}

// ---------------- K8: attention pool + hybrid transform + layernorm -> a_h (f16) --
__global__ __launch_bounds__(128) void k_attn(
    const float* __restrict__ Hbuf, const float* __restrict__ q,
    const float* __restrict__ b1, const float* __restrict__ b2,
    const float* __restrict__ w3, const float* __restrict__ Wt,
    const float* __restrict__ bt, const float* __restrict__ gamma,
    const float* __restrict__ beta, _Float16* __restrict__ a_h) {
  __shared__ float red[2];
  __shared__ float cat[256];
  const int b = blockIdx.x, t = threadIdx.x;
  float q1b = q[(size_t)(B_*L_ + b)*H_ + t] + b1[t] + b2[t];
  float w3t = w3[t];
  float at = 0.f;
  for (int l = 0; l < L_; l++) {
    float s = q1b + q[(size_t)(b*L_ + l)*H_ + t];
    float v = (1.f/(1.f + __expf(-s))) * w3t;
    #pragma unroll
    for (int o = 32; o > 0; o >>= 1) v += __shfl_down(v, o);
    if ((t & 63) == 0) red[t >> 6] = v;
    __syncthreads();
    float alpha = red[0] + red[1];
    __syncthreads();
    at += alpha * Hbuf[(size_t)(b*L_ + l)*H_ + t];  // hidden==0 at masked positions
  }
  float htv = Hbuf[(size_t)(B_*L_ + b)*H_ + t];
  cat[t] = at; cat[128 + t] = htv;
  __syncthreads();
  float hyb = bt[t];
  const float* wrow = &Wt[(size_t)t*256];
  #pragma unroll 4
  for (int k = 0; k < 256; k++) hyb += cat[k]*wrow[k];
  // layernorm over 128
  float s = hyb;
  #pragma unroll
  for (int o = 32; o > 0; o >>= 1) s += __shfl_down(s, o);
  if ((t & 63) == 0) red[t >> 6] = s;
  __syncthreads();
  float mu = (red[0] + red[1]) * (1.f/128.f);
  __syncthreads();
  float d = hyb - mu;
  float s2 = d*d;
  #pragma unroll
  for (int o = 32; o > 0; o >>= 1) s2 += __shfl_down(s2, o);
  if ((t & 63) == 0) red[t >> 6] = s2;
  __syncthreads();
  float var = (red[0] + red[1]) * (1.f/128.f);
  float y = d * rsqrtf(var + 1e-5f) * gamma[t] + beta[t];
  a_h[(size_t)b*H_ + t] = (_Float16)y;
}

// ---------------- K9: scores = a * emb[1:]^T  [512, 99999] fp32 out --------------
// grid (1563 n-tiles, 4 m-groups of 128 rows); block 256 = 4 waves; wave: 32x64 tile
__global__ __launch_bounds__(256) void k_scores(
    const _Float16* __restrict__ a_h, const float* __restrict__ emb,
    float* __restrict__ out) {
  __shared__ _Float16 lds_a[128*PITCH];
  __shared__ _Float16 lds_b[64*PITCH];
  const int tid = threadIdx.x;
  const int nt = blockIdx.x, mg = blockIdx.y;
  // stage A: 128 rows x 128 f16 = 2048 uint4-chunks = 8*256
  #pragma unroll
  for (int i = 0; i < 8; i++) {
    int lin = i*256 + tid;
    int row = lin >> 4, ch = lin & 15;
    uint4 v = *reinterpret_cast<const uint4*>(&a_h[(size_t)(mg*128 + row)*H_ + ch*8]);
    *reinterpret_cast<uint4*>(&lds_a[row*PITCH + ch*8]) = v;
  }
  // stage B: 64 emb rows fp32 -> f16 (guard last tile): 2048 float4-chunks
  #pragma unroll
  for (int i = 0; i < 8; i++) {
    int lin = i*256 + tid;
    int row = lin >> 5, c4 = lin & 31;
    int g = nt*64 + row;
    float4 v = {0.f, 0.f, 0.f, 0.f};
    if (g < NV) v = *reinterpret_cast<const float4*>(&emb[(size_t)(1 + g)*H_ + c4*4]);
    union { _Float16 h[4]; uint2 u; } p;
    p.h[0]=(_Float16)v.x; p.h[1]=(_Float16)v.y; p.h[2]=(_Float16)v.z; p.h[3]=(_Float16)v.w;
    *reinterpret_cast<uint2*>(&lds_b[row*PITCH + c4*4]) = p.u;
  }
  __syncthreads();
  const int w = tid >> 6, lane = tid & 63, quad = lane >> 4, r16 = lane & 15;
  half8 afr[2][4];
  #pragma unroll
  for (int ms = 0; ms < 2; ms++)
    #pragma unroll
    for (int kk = 0; kk < 4; kk++)
      afr[ms][kk] = *reinterpret_cast<const half8*>(&lds_a[(w*32 + ms*16 + r16)*PITCH + kk*32 + quad*8]);
  floatx4 acc[2][4];
  #pragma unroll
  for (int ms = 0; ms < 2; ms++)
    #pragma unroll
    for (int n4 = 0; n4 < 4; n4++) acc[ms][n4] = (floatx4){0.f,0.f,0.f,0.f};
  #pragma unroll
  for (int n4 = 0; n4 < 4; n4++) {
    #pragma unroll
    for (int kk = 0; kk < 4; kk++) {
      half8 bfr = *reinterpret_cast<const half8*>(&lds_b[(n4*16 + r16)*PITCH + kk*32 + quad*8]);
      acc[0][n4] = __builtin_amdgcn_mfma_f32_16x16x32_f16(afr[0][kk], bfr, acc[0][n4], 0, 0, 0);
      acc[1][n4] = __builtin_amdgcn_mfma_f32_16x16x32_f16(afr[1][kk], bfr, acc[1][n4], 0, 0, 0);
    }
  }
  #pragma unroll
  for (int ms = 0; ms < 2; ms++)
    #pragma unroll
    for (int n4 = 0; n4 < 4; n4++)
      #pragma unroll
      for (int r = 0; r < 4; r++) {
        int row = mg*128 + w*32 + ms*16 + quad*4 + r;
        int col = nt*64 + n4*16 + r16;
        if (col < NV) out[(size_t)row*NV + col] = acc[ms][n4][r];
      }
}

extern "C" void kernel_launch(void* const* d_in, const int* in_sizes, int n_in,
                              void* d_out, int out_size, void* d_ws, size_t ws_size,
                              hipStream_t stream) {
  const int*   items     = (const int*)d_in[0];
  const int*   edge_index= (const int*)d_in[1];
  const int*   sequence  = (const int*)d_in[2];
  const int*   mask      = (const int*)d_in[3];
  const float* emb       = (const float*)d_in[4];
  const float* ggnn_w    = (const float*)d_in[5];
  const float* W_ih      = (const float*)d_in[6];
  const float* W_hh      = (const float*)d_in[7];
  const float* b_ih      = (const float*)d_in[8];
  const float* b_hh      = (const float*)d_in[9];
  const float* W1        = (const float*)d_in[10];
  const float* b1        = (const float*)d_in[11];
  const float* W2        = (const float*)d_in[12];
  const float* b2        = (const float*)d_in[13];
  const float* w3        = (const float*)d_in[14];
  const float* Wt        = (const float*)d_in[15];
  const float* bt        = (const float*)d_in[16];
  const float* gamma     = (const float*)d_in[17];
  const float* beta      = (const float*)d_in[18];

  char* ws = (char*)d_ws;
  // buffer layout (time-multiplexed, ~39.5 MB total)
  float* x    = (float*)(ws + 0);              // 8192x128, becomes xg in-place
  float* mgh  = (float*)(ws + 4194304);        // 8192x512: [m | gh]
  float* q    = (float*)(ws + 4194304);        // reuses mgh region after K5
  float* agg  = (float*)(ws + 20971520);       // 8192x128
  float* Hbuf = (float*)(ws + 20971520);       // 10752x128, overlays agg (dead by K6)
  float* gi   = (float*)(ws + 26476544);       // 8192x384
  _Float16* a_h   = (_Float16*)(ws + 39059456);
  _Float16* WgT_h = (_Float16*)(ws + 39190528);
  _Float16* Whh_h = (_Float16*)(ws + 39223296); // contiguous after WgT_h (B = [WgT;Whh])
  _Float16* Wih_h = (_Float16*)(ws + 39321600);
  _Float16* W2_h  = (_Float16*)(ws + 39419904);
  _Float16* W1_h  = (_Float16*)(ws + 39452672);
  float* out = (float*)d_out;

  // K1: prep (x gather + f16 weight conversions)
  k_prep<<<4672, 256, 0, stream>>>(items, emb, ggnn_w, W_hh, W_ih, W2, W1,
                                   x, WgT_h, Whh_h, Wih_h, W2_h, W1_h);
  // K2: mgh = x * [WgT ; Whh]^T   (m and gh fused, N=512)
  k_gemm128<<<dim3(8, 128), 256, 0, stream>>>(x, WgT_h, WgT_h, 1 << 30, mgh, 512);
  // K3: agg = segment_sum(m[src], dst)
  k_scatter<<<512, 128, 0, stream>>>(edge_index, mgh, agg);
  // K4: gi = agg * Wih^T (N=384)
  k_gemm128<<<dim3(6, 128), 256, 0, stream>>>(agg, Wih_h, Wih_h, 1 << 30, gi, 384);
  // K5: GRU update (x -> xg in place)
  k_gru<<<4096, 256, 0, stream>>>(gi, mgh, b_ih, b_hh, x);
  // K6: hidden + ht rows
  k_hidden<<<5376, 256, 0, stream>>>(items, sequence, mask, x, emb, Hbuf);
  // K7: q = Hbuf * W2^T (rows<10240) / W1^T (ht rows); N=128
  k_gemm128<<<dim3(2, 168), 256, 0, stream>>>(Hbuf, W2_h, W1_h, 160, q, 128);
  // K8: attention pooling + hybrid + layernorm -> a_h (f16)
  k_attn<<<512, 128, 0, stream>>>(Hbuf, q, b1, b2, w3, Wt, bt, gamma, beta, a_h);
  // K9: scores = a * emb[1:]^T
  k_scores<<<dim3(1563, 4), 256, 0, stream>>>(a_h, emb, out);
}